// Round 1
// baseline (196.925 us; speedup 1.0000x reference)
//
#include <hip/hip_runtime.h>
#include <math.h>

#define KPOT 5

// One thread handles 4 consecutive rows:
//   x/noise/out chunk: 8 floats = 2 x float4 (32 B, 16B-aligned since 32*t)
//   gumbel chunk: 20 floats = 5 x float4 (80 B, 16B-aligned since 80*t)
__global__ __launch_bounds__(256) void lightsb_kernel(
    const float* __restrict__ x,
    const float* __restrict__ r,
    const float* __restrict__ log_S,
    const float* __restrict__ log_alpha,
    const float* __restrict__ gumbel,
    const float* __restrict__ noise,
    float* __restrict__ out,
    int n_rows)
{
    const int t = blockIdx.x * blockDim.x + threadIdx.x;
    const long long row0 = (long long)t * 4;
    if (row0 >= n_rows) return;

    // Per-k constants — uniform addresses, L1/L2-cached broadcast loads.
    float S0[KPOT], S1[KPOT], r0[KPOT], r1[KPOT], la[KPOT], q0[KPOT], q1[KPOT];
#pragma unroll
    for (int k = 0; k < KPOT; ++k) {
        float s0 = expf(log_S[2 * k + 0]);
        float s1 = expf(log_S[2 * k + 1]);
        S0[k] = s0;
        S1[k] = s1;
        r0[k] = r[2 * k + 0];
        r1[k] = r[2 * k + 1];
        la[k] = log_alpha[k];
        q0[k] = sqrtf(s0);   // EPS = 1.0
        q1[k] = sqrtf(s1);
    }

    if (row0 + 4 <= n_rows) {
        // -------- fully vectorized path --------
        const float4* x4 = reinterpret_cast<const float4*>(x + row0 * 2);
        const float4* n4 = reinterpret_cast<const float4*>(noise + row0 * 2);
        const float4* g4 = reinterpret_cast<const float4*>(gumbel + row0 * 5);

        float4 xa = x4[0], xb = x4[1];
        float4 na = n4[0], nb = n4[1];
        float4 ga = g4[0], gb = g4[1], gc = g4[2], gd = g4[3], ge = g4[4];

        float xs[8] = {xa.x, xa.y, xa.z, xa.w, xb.x, xb.y, xb.z, xb.w};
        float ns[8] = {na.x, na.y, na.z, na.w, nb.x, nb.y, nb.z, nb.w};
        float gs[20] = {ga.x, ga.y, ga.z, ga.w,
                        gb.x, gb.y, gb.z, gb.w,
                        gc.x, gc.y, gc.z, gc.w,
                        gd.x, gd.y, gd.z, gd.w,
                        ge.x, ge.y, ge.z, ge.w};
        float os[8];

#pragma unroll
        for (int j = 0; j < 4; ++j) {
            float x0 = xs[2 * j + 0];
            float x1 = xs[2 * j + 1];
            float u0 = 0.5f * x0 * x0;
            float u1 = 0.5f * x1 * x1;

            // logits_k = S0*u0 + S1*u1 + r0*x0 + r1*x1 + la   (EPS = 1)
            float best = fmaf(S0[0], u0, fmaf(S1[0], u1,
                         fmaf(r0[0], x0, fmaf(r1[0], x1, la[0] + gs[5 * j + 0]))));
            float bS0 = S0[0], bS1 = S1[0];
            float br0 = r0[0], br1 = r1[0];
            float bq0 = q0[0], bq1 = q1[0];
#pragma unroll
            for (int k = 1; k < KPOT; ++k) {
                float s = fmaf(S0[k], u0, fmaf(S1[k], u1,
                          fmaf(r0[k], x0, fmaf(r1[k], x1, la[k] + gs[5 * j + k]))));
                bool c = s > best;          // strict > keeps first max (jnp.argmax)
                best = c ? s : best;
                bS0 = c ? S0[k] : bS0;
                bS1 = c ? S1[k] : bS1;
                br0 = c ? r0[k] : br0;
                br1 = c ? r1[k] : br1;
                bq0 = c ? q0[k] : bq0;
                bq1 = c ? q1[k] : bq1;
            }
            // out = r_k + S_k*x + sqrt(S_k)*noise
            os[2 * j + 0] = fmaf(bS0, x0, fmaf(bq0, ns[2 * j + 0], br0));
            os[2 * j + 1] = fmaf(bS1, x1, fmaf(bq1, ns[2 * j + 1], br1));
        }

        float4* o4 = reinterpret_cast<float4*>(out + row0 * 2);
        o4[0] = make_float4(os[0], os[1], os[2], os[3]);
        o4[1] = make_float4(os[4], os[5], os[6], os[7]);
    } else {
        // -------- scalar tail (only if n_rows % 4 != 0) --------
        for (long long row = row0; row < n_rows; ++row) {
            float x0 = x[row * 2 + 0];
            float x1 = x[row * 2 + 1];
            float u0 = 0.5f * x0 * x0;
            float u1 = 0.5f * x1 * x1;
            float best = fmaf(S0[0], u0, fmaf(S1[0], u1,
                         fmaf(r0[0], x0, fmaf(r1[0], x1, la[0] + gumbel[row * 5 + 0]))));
            int bidx = 0;
#pragma unroll
            for (int k = 1; k < KPOT; ++k) {
                float s = fmaf(S0[k], u0, fmaf(S1[k], u1,
                          fmaf(r0[k], x0, fmaf(r1[k], x1, la[k] + gumbel[row * 5 + k]))));
                if (s > best) { best = s; bidx = k; }
            }
            float n0 = noise[row * 2 + 0];
            float n1 = noise[row * 2 + 1];
            out[row * 2 + 0] = fmaf(S0[bidx], x0, fmaf(q0[bidx], n0, r0[bidx]));
            out[row * 2 + 1] = fmaf(S1[bidx], x1, fmaf(q1[bidx], n1, r1[bidx]));
        }
    }
}

extern "C" void kernel_launch(void* const* d_in, const int* in_sizes, int n_in,
                              void* d_out, int out_size, void* d_ws, size_t ws_size,
                              hipStream_t stream) {
    const float* x         = (const float*)d_in[0];
    const float* r         = (const float*)d_in[1];
    const float* log_S     = (const float*)d_in[2];
    const float* log_alpha = (const float*)d_in[3];
    const float* gumbel    = (const float*)d_in[4];
    const float* noise     = (const float*)d_in[5];
    float* out = (float*)d_out;

    const int n_rows = in_sizes[0] / 2;            // DIM = 2
    const int n_threads = (n_rows + 3) / 4;        // 4 rows per thread
    const int block = 256;
    const int grid = (n_threads + block - 1) / block;

    lightsb_kernel<<<grid, block, 0, stream>>>(x, r, log_S, log_alpha,
                                               gumbel, noise, out, n_rows);
}